// Round 1
// baseline (158.491 us; speedup 1.0000x reference)
//
#include <hip/hip_runtime.h>
#include <math.h>

#define N_NODES 100000
#define D_EMB   64
#define NB      64
#define KSEL    500000
#define NMENT   200000
#define ATT_H   20

// ws layout (float offsets)
#define WS_EB    0          // [100000]  per-node exp(beta)
#define WS_NUM   100000     // [64*64]   portrait numerator (atomic accum)
#define WS_DEN   104096     // [64]      portrait denominator
#define WS_PORT  104160     // [64*64]   normalized portrait
#define WS_W     108256     // [2*64]    layer weights (sigmoid)

// ---------------------------------------------------------------------------
// Kernel P: per-node attention potential eb[n] = exp(tanh(ge[n] @ Wt) @ V)
// Also zeroes the num/den accumulators (tid < 4160).
// ---------------------------------------------------------------------------
__global__ __launch_bounds__(256) void kP(const float* __restrict__ ge,
                                          const float* __restrict__ attW,
                                          const float* __restrict__ attV,
                                          float* __restrict__ ws) {
    int tid = blockIdx.x * 256 + threadIdx.x;
    if (tid < 64 * 64 + 64) ws[WS_NUM + tid] = 0.f;   // zero num + den
    if (tid >= N_NODES) return;

    const float4* g4 = (const float4*)(ge + (size_t)tid * D_EMB);
    float4 x[16];
#pragma unroll
    for (int i = 0; i < 16; ++i) x[i] = g4[i];

    float beta = 0.f;
#pragma unroll
    for (int j = 0; j < ATT_H; ++j) {
        float h = 0.f;
#pragma unroll
        for (int i = 0; i < 16; ++i) {
            float4 w = ((const float4*)(attW + j * D_EMB))[i];  // uniform -> s_load
            h += w.x * x[i].x + w.y * x[i].y + w.z * x[i].z + w.w * x[i].w;
        }
        beta += attV[j] * tanhf(h);
    }
    ws[WS_EB + tid] = expf(beta);
}

// ---------------------------------------------------------------------------
// Kernel A2: segment accumulation of exp_beta and exp_beta*embed per batch.
// mention_batch_index is sorted -> local accumulate, flush on batch change.
// One 64-lane group per mention; lane d handles dim d.
// ---------------------------------------------------------------------------
__global__ __launch_bounds__(256) void kA2(const float* __restrict__ ge,
                                           const int* __restrict__ mi,
                                           const int* __restrict__ mbi,
                                           float* __restrict__ ws) {
    int lane = threadIdx.x & 63;
    int grp  = threadIdx.x >> 6;
    int nblocks = gridDim.x;
    int per_block = (NMENT + nblocks - 1) / nblocks;
    int bstart = blockIdx.x * per_block;
    int bend   = min(bstart + per_block, NMENT);
    int blen   = bend - bstart;
    if (blen <= 0) return;
    int per_grp = (blen + 3) >> 2;
    int gstart = bstart + grp * per_grp;
    int gend   = min(gstart + per_grp, bend);

    float acc = 0.f, dacc = 0.f;
    int cur_b = -1;
    for (int i = gstart; i < gend; ++i) {
        int b = mbi[i];
        if (b != cur_b) {
            if (cur_b >= 0) {
                atomicAdd(&ws[WS_NUM + cur_b * 64 + lane], acc);
                if (lane == 0) atomicAdd(&ws[WS_DEN + cur_b], dacc);
            }
            acc = 0.f; dacc = 0.f; cur_b = b;
        }
        int nd = mi[i];
        float eb = ws[WS_EB + nd];
        float x  = ge[(size_t)nd * D_EMB + lane];
        acc = fmaf(eb, x, acc);
        dacc += eb;
    }
    if (cur_b >= 0) {
        atomicAdd(&ws[WS_NUM + cur_b * 64 + lane], acc);
        if (lane == 0) atomicAdd(&ws[WS_DEN + cur_b], dacc);
    }
}

// ---------------------------------------------------------------------------
// Kernel BW: normalize portrait + compute layer gate weights.
// Grid: 128 blocks = (layer, group); 64 threads (lane d = dim d).
// ---------------------------------------------------------------------------
__global__ __launch_bounds__(64) void kBW(const float* __restrict__ ge,
                                          const float* __restrict__ utter,
                                          const int* __restrict__ grpb,
                                          const int* __restrict__ lastI,
                                          const int* __restrict__ intentI,
                                          const float* __restrict__ W1w,
                                          const float* __restrict__ W1b,
                                          const float* __restrict__ W2w,
                                          const float* __restrict__ W2b,
                                          const float* __restrict__ intentEmb,
                                          float* __restrict__ ws) {
    int bi = blockIdx.x;         // 0..127
    int l  = bi >> 6;
    int g  = bi & 63;
    int d  = threadIdx.x;

    if (l == 0) {
        // write normalized portrait once (batch index == g here)
        ws[WS_PORT + g * 64 + d] = ws[WS_NUM + g * 64 + d] / ws[WS_DEN + g];
    }
    int gb = grpb[bi];
    float pd = ws[WS_NUM + gb * 64 + d] / ws[WS_DEN + gb];

    int last = lastI[bi];
    float gl = (last < N_NODES) ? ge[(size_t)last * D_EMB + d] : 0.f;
    int it = intentI[bi];
    float ie = intentEmb[it * D_EMB + d];

    const float* Ww = (l == 0) ? W1w : W2w;
    float bias      = (l == 0) ? W1b[0] : W2b[0];

    float val = utter[gb * D_EMB + d] * Ww[d]
              + pd * Ww[64 + d]
              + gl * Ww[128 + d]
              + ie * Ww[192 + d];
#pragma unroll
    for (int off = 32; off; off >>= 1) val += __shfl_xor(val, off);
    if (d == 0) ws[WS_W + bi] = 1.f / (1.f + expf(-(val + bias)));
}

// ---------------------------------------------------------------------------
// Kernel C: main scoring. 16 lanes per k (4 k's per wave).
// out[k] = sum_d (c_u*utter[b][d] + c_p*portrait[b][d]) * graph_e[node][d]
// layer 0: c_u = w0[g], c_p = 1-w0[g]
// layer 1: c_u = w0[b] + mask*w1[g], c_p = (1-w0[b]) + mask*(1-w1[g])
// ---------------------------------------------------------------------------
__global__ __launch_bounds__(256) void kC(const float* __restrict__ ge,
                                          const float* __restrict__ utter,
                                          const int* __restrict__ sel,
                                          const int* __restrict__ selb,
                                          const int* __restrict__ selg,
                                          const float* __restrict__ masks,
                                          const float* __restrict__ ws,
                                          float* __restrict__ out) {
    __shared__ float4 sU[64 * 17];   // utter, f4-stride 17 (dword stride 68)
    __shared__ float4 sP[64 * 17];   // portrait
    __shared__ float  sW[128];       // gate weights

    for (int i = threadIdx.x; i < 64 * 16; i += 256) {
        int r = i >> 4, c = i & 15;
        sU[r * 17 + c] = ((const float4*)utter)[i];
        sP[r * 17 + c] = ((const float4*)(ws + WS_PORT))[i];
    }
    if (threadIdx.x < 128) sW[threadIdx.x] = ws[WS_W + threadIdx.x];
    __syncthreads();

    int lane = threadIdx.x & 63;
    int widb = threadIdx.x >> 6;
    int wave = blockIdx.x * 4 + widb;
    int totalWaves = gridDim.x * 4;
    int grp = lane >> 4;     // which of 4 k's this lane serves
    int lp  = lane & 15;     // position within the k-group (4 dims each)

    const float4* g4 = (const float4*)ge;

    for (int k0 = wave * 4; k0 < 2 * KSEL; k0 += totalWaves * 4) {
        int kk = k0 + grp;
        if (kk < 2 * KSEL) {
            int node = sel[kk];
            int b    = selb[kk];
            int g    = selg[kk];
            float cu, cp;
            if (kk < KSEL) {
                float w = sW[g];
                cu = w; cp = 1.f - w;
            } else {
                float mask = masks[kk];
                float lw = sW[b];
                float w1 = sW[64 + g];
                cu = fmaf(mask, w1, lw);
                cp = fmaf(mask, 1.f - w1, 1.f - lw);
            }
            float4 f = make_float4(0.f, 0.f, 0.f, 0.f);
            if (node < N_NODES) f = g4[(size_t)node * 16 + lp];
            float4 tu = sU[b * 17 + lp];
            float4 tp = sP[b * 17 + lp];
            float val = (cu * tu.x + cp * tp.x) * f.x
                      + (cu * tu.y + cp * tp.y) * f.y
                      + (cu * tu.z + cp * tp.z) * f.z
                      + (cu * tu.w + cp * tp.w) * f.w;
            val += __shfl_xor(val, 1);
            val += __shfl_xor(val, 2);
            val += __shfl_xor(val, 4);
            val += __shfl_xor(val, 8);
            if (lp == 0) out[kk] = val;
        }
    }
}

extern "C" void kernel_launch(void* const* d_in, const int* in_sizes, int n_in,
                              void* d_out, int out_size, void* d_ws, size_t ws_size,
                              hipStream_t stream) {
    const float* ge        = (const float*)d_in[0];
    const float* utter     = (const float*)d_in[1];
    const int*   mi        = (const int*)d_in[2];
    const int*   mbi       = (const int*)d_in[3];
    const int*   sel       = (const int*)d_in[4];
    const int*   selb      = (const int*)d_in[5];
    const int*   selg      = (const int*)d_in[6];
    const int*   grpb      = (const int*)d_in[7];
    const int*   lastI     = (const int*)d_in[8];
    const int*   intentI   = (const int*)d_in[9];
    const float* masks     = (const float*)d_in[10];
    const float* attW      = (const float*)d_in[11];
    const float* attV      = (const float*)d_in[12];
    const float* W1w       = (const float*)d_in[13];
    const float* W1b       = (const float*)d_in[14];
    const float* W2w       = (const float*)d_in[15];
    const float* W2b       = (const float*)d_in[16];
    const float* intentEmb = (const float*)d_in[17];
    float* ws  = (float*)d_ws;
    float* out = (float*)d_out;

    kP <<<dim3((N_NODES + 255) / 256), dim3(256), 0, stream>>>(ge, attW, attV, ws);
    kA2<<<dim3(1024), dim3(256), 0, stream>>>(ge, mi, mbi, ws);
    kBW<<<dim3(128), dim3(64), 0, stream>>>(ge, utter, grpb, lastI, intentI,
                                            W1w, W1b, W2w, W2b, intentEmb, ws);
    kC <<<dim3(1024), dim3(256), 0, stream>>>(ge, utter, sel, selb, selg, masks, ws, out);
}

// Round 2
// 147.245 us; speedup vs baseline: 1.0764x; 1.0764x over previous
//
#include <hip/hip_runtime.h>
#include <math.h>

#define N_NODES 100000
#define D_EMB   64
#define NB      64
#define KSEL    500000
#define NMENT   200000
#define ATT_H   20

// ws layout (float offsets)
#define WS_EB    0          // [100000]  per-node exp(beta)
#define WS_NUM   100000     // [64*64]   portrait numerator (atomic accum)
#define WS_DEN   104096     // [64]      portrait denominator
#define WS_PORT  104160     // [64*64]   normalized portrait
#define WS_W     108256     // [2*64]    layer weights (sigmoid)

// ---------------------------------------------------------------------------
// Kernel P: per-node attention potential eb[n] = exp(tanh(ge[n] @ Wt) @ V)
// Also zeroes the num/den accumulators (tid < 4160).
// ---------------------------------------------------------------------------
__global__ __launch_bounds__(256) void kP(const float* __restrict__ ge,
                                          const float* __restrict__ attW,
                                          const float* __restrict__ attV,
                                          float* __restrict__ ws) {
    int tid = blockIdx.x * 256 + threadIdx.x;
    if (tid < 64 * 64 + 64) ws[WS_NUM + tid] = 0.f;   // zero num + den
    if (tid >= N_NODES) return;

    const float4* g4 = (const float4*)(ge + (size_t)tid * D_EMB);
    float4 x[16];
#pragma unroll
    for (int i = 0; i < 16; ++i) x[i] = g4[i];

    float beta = 0.f;
#pragma unroll
    for (int j = 0; j < ATT_H; ++j) {
        float h = 0.f;
#pragma unroll
        for (int i = 0; i < 16; ++i) {
            float4 w = ((const float4*)(attW + j * D_EMB))[i];  // uniform -> s_load
            h += w.x * x[i].x + w.y * x[i].y + w.z * x[i].z + w.w * x[i].w;
        }
        beta += attV[j] * tanhf(h);
    }
    ws[WS_EB + tid] = expf(beta);
}

// ---------------------------------------------------------------------------
// Kernel A2: segment accumulation of exp_beta and exp_beta*embed per batch.
// Independent iterations (no carried state): LDS per-batch accumulators via
// ds_add_f32 (lanes -> consecutive banks, conflict-free). Sorted batch index
// => each block's strip spans ~1-2 batches; flush only that range.
// ---------------------------------------------------------------------------
__global__ __launch_bounds__(256) void kA2(const float* __restrict__ ge,
                                           const int* __restrict__ mi,
                                           const int* __restrict__ mbi,
                                           float* __restrict__ ws) {
    __shared__ float lnum[64][64];
    __shared__ float lden[64];
    for (int i = threadIdx.x; i < 64 * 64; i += 256) ((float*)lnum)[i] = 0.f;
    if (threadIdx.x < 64) lden[threadIdx.x] = 0.f;
    __syncthreads();

    int lane = threadIdx.x & 63;
    int wid  = threadIdx.x >> 6;
    int per_block = (NMENT + gridDim.x - 1) / gridDim.x;
    int bstart = blockIdx.x * per_block;
    int bend   = min(bstart + per_block, NMENT);
    if (bstart < bend) {
        for (int i = bstart + wid; i < bend; i += 4) {
            int b  = mbi[i];
            int nd = mi[i];
            float eb = ws[WS_EB + nd];
            float x  = ge[(size_t)nd * D_EMB + lane];
            atomicAdd(&lnum[b][lane], eb * x);
            if (lane == 0) atomicAdd(&lden[b], eb);
        }
    }
    __syncthreads();
    if (bstart >= bend) return;
    int b0 = mbi[bstart], b1 = mbi[bend - 1];
    for (int b = b0 + wid; b <= b1; b += 4) {
        atomicAdd(&ws[WS_NUM + b * 64 + lane], lnum[b][lane]);
        if (lane == 0) atomicAdd(&ws[WS_DEN + b], lden[b]);
    }
}

// ---------------------------------------------------------------------------
// Kernel BW: normalize portrait + compute layer gate weights.
// Grid: 128 blocks = (layer, group); 64 threads (lane d = dim d).
// ---------------------------------------------------------------------------
__global__ __launch_bounds__(64) void kBW(const float* __restrict__ ge,
                                          const float* __restrict__ utter,
                                          const int* __restrict__ grpb,
                                          const int* __restrict__ lastI,
                                          const int* __restrict__ intentI,
                                          const float* __restrict__ W1w,
                                          const float* __restrict__ W1b,
                                          const float* __restrict__ W2w,
                                          const float* __restrict__ W2b,
                                          const float* __restrict__ intentEmb,
                                          float* __restrict__ ws) {
    int bi = blockIdx.x;         // 0..127
    int l  = bi >> 6;
    int g  = bi & 63;
    int d  = threadIdx.x;

    if (l == 0) {
        // write normalized portrait once (batch index == g here)
        ws[WS_PORT + g * 64 + d] = ws[WS_NUM + g * 64 + d] / ws[WS_DEN + g];
    }
    int gb = grpb[bi];
    float pd = ws[WS_NUM + gb * 64 + d] / ws[WS_DEN + gb];

    int last = lastI[bi];
    float gl = (last < N_NODES) ? ge[(size_t)last * D_EMB + d] : 0.f;
    int it = intentI[bi];
    float ie = intentEmb[it * D_EMB + d];

    const float* Ww = (l == 0) ? W1w : W2w;
    float bias      = (l == 0) ? W1b[0] : W2b[0];

    float val = utter[gb * D_EMB + d] * Ww[d]
              + pd * Ww[64 + d]
              + gl * Ww[128 + d]
              + ie * Ww[192 + d];
#pragma unroll
    for (int off = 32; off; off >>= 1) val += __shfl_xor(val, off);
    if (d == 0) ws[WS_W + bi] = 1.f / (1.f + expf(-(val + bias)));
}

// ---------------------------------------------------------------------------
// Kernel C: main scoring. 16 lanes per k (4 k's per wave), 512-thread blocks
// so LDS (35.3KB) and threads both allow 4 blocks/CU -> 32 waves/CU (100%).
// out[k] = sum_d (c_u*utter[b][d] + c_p*portrait[b][d]) * graph_e[node][d]
// layer 0: c_u = w0[g], c_p = 1-w0[g]
// layer 1: c_u = w0[b] + mask*w1[g], c_p = (1-w0[b]) + mask*(1-w1[g])
// ---------------------------------------------------------------------------
__global__ __launch_bounds__(512, 8) void kC(const float* __restrict__ ge,
                                             const float* __restrict__ utter,
                                             const int* __restrict__ sel,
                                             const int* __restrict__ selb,
                                             const int* __restrict__ selg,
                                             const float* __restrict__ masks,
                                             const float* __restrict__ ws,
                                             float* __restrict__ out) {
    __shared__ float4 sU[64 * 17];   // utter, f4-stride 17 (dword stride 68)
    __shared__ float4 sP[64 * 17];   // portrait
    __shared__ float  sW[128];       // gate weights

    for (int i = threadIdx.x; i < 64 * 16; i += 512) {
        int r = i >> 4, c = i & 15;
        sU[r * 17 + c] = ((const float4*)utter)[i];
        sP[r * 17 + c] = ((const float4*)(ws + WS_PORT))[i];
    }
    if (threadIdx.x < 128) sW[threadIdx.x] = ws[WS_W + threadIdx.x];
    __syncthreads();

    int lane = threadIdx.x & 63;
    int widb = threadIdx.x >> 6;
    int wave = blockIdx.x * 8 + widb;
    int totalWaves = gridDim.x * 8;
    int grp = lane >> 4;     // which of 4 k's this lane serves
    int lp  = lane & 15;     // position within the k-group (4 dims each)

    const float4* g4 = (const float4*)ge;

    for (int k0 = wave * 4; k0 < 2 * KSEL; k0 += totalWaves * 4) {
        int kk = k0 + grp;
        if (kk < 2 * KSEL) {
            int node = sel[kk];
            int b    = selb[kk];
            int g    = selg[kk];
            float cu, cp;
            if (kk < KSEL) {
                float w = sW[g];
                cu = w; cp = 1.f - w;
            } else {
                float mask = masks[kk];
                float lw = sW[b];
                float w1 = sW[64 + g];
                cu = fmaf(mask, w1, lw);
                cp = fmaf(mask, 1.f - w1, 1.f - lw);
            }
            float4 f = make_float4(0.f, 0.f, 0.f, 0.f);
            if (node < N_NODES) f = g4[(size_t)node * 16 + lp];
            float4 tu = sU[b * 17 + lp];
            float4 tp = sP[b * 17 + lp];
            float val = (cu * tu.x + cp * tp.x) * f.x
                      + (cu * tu.y + cp * tp.y) * f.y
                      + (cu * tu.z + cp * tp.z) * f.z
                      + (cu * tu.w + cp * tp.w) * f.w;
            val += __shfl_xor(val, 1);
            val += __shfl_xor(val, 2);
            val += __shfl_xor(val, 4);
            val += __shfl_xor(val, 8);
            if (lp == 0) out[kk] = val;
        }
    }
}

extern "C" void kernel_launch(void* const* d_in, const int* in_sizes, int n_in,
                              void* d_out, int out_size, void* d_ws, size_t ws_size,
                              hipStream_t stream) {
    const float* ge        = (const float*)d_in[0];
    const float* utter     = (const float*)d_in[1];
    const int*   mi        = (const int*)d_in[2];
    const int*   mbi       = (const int*)d_in[3];
    const int*   sel       = (const int*)d_in[4];
    const int*   selb      = (const int*)d_in[5];
    const int*   selg      = (const int*)d_in[6];
    const int*   grpb      = (const int*)d_in[7];
    const int*   lastI     = (const int*)d_in[8];
    const int*   intentI   = (const int*)d_in[9];
    const float* masks     = (const float*)d_in[10];
    const float* attW      = (const float*)d_in[11];
    const float* attV      = (const float*)d_in[12];
    const float* W1w       = (const float*)d_in[13];
    const float* W1b       = (const float*)d_in[14];
    const float* W2w       = (const float*)d_in[15];
    const float* W2b       = (const float*)d_in[16];
    const float* intentEmb = (const float*)d_in[17];
    float* ws  = (float*)d_ws;
    float* out = (float*)d_out;

    kP <<<dim3((N_NODES + 255) / 256), dim3(256), 0, stream>>>(ge, attW, attV, ws);
    kA2<<<dim3(1024), dim3(256), 0, stream>>>(ge, mi, mbi, ws);
    kBW<<<dim3(128), dim3(64), 0, stream>>>(ge, utter, grpb, lastI, intentI,
                                            W1w, W1b, W2w, W2b, intentEmb, ws);
    kC <<<dim3(1024), dim3(512), 0, stream>>>(ge, utter, sel, selb, selg, masks, ws, out);
}

// Round 6
// 120.240 us; speedup vs baseline: 1.3181x; 1.2246x over previous
//
#include <hip/hip_runtime.h>
#include <math.h>

#define N_NODES 100000
#define D_EMB   64
#define NB      64
#define KSEL    500000
#define NMENT   200000
#define ATT_H   20

// ws layout (float offsets)
#define WS_EB    0          // [100000]  per-node exp(beta)
#define WS_NUM   100000     // [64*64]   portrait numerator (atomic accum)
#define WS_DEN   104096     // [64]      portrait denominator
#define WS_PORT  104160     // [64*64]   normalized portrait
#define WS_W     108256     // [2*64]    layer weights (sigmoid)

// ---------------------------------------------------------------------------
// Kernel P: per-node attention potential eb[n] = exp(tanh(ge[n] @ Wt) @ V)
// Also zeroes the num/den accumulators (tid < 4160).
// ---------------------------------------------------------------------------
__global__ __launch_bounds__(256) void kP(const float* __restrict__ ge,
                                          const float* __restrict__ attW,
                                          const float* __restrict__ attV,
                                          float* __restrict__ ws) {
    int tid = blockIdx.x * 256 + threadIdx.x;
    if (tid < 64 * 64 + 64) ws[WS_NUM + tid] = 0.f;   // zero num + den
    if (tid >= N_NODES) return;

    const float4* g4 = (const float4*)(ge + (size_t)tid * D_EMB);
    float4 x[16];
#pragma unroll
    for (int i = 0; i < 16; ++i) x[i] = g4[i];

    float beta = 0.f;
#pragma unroll
    for (int j = 0; j < ATT_H; ++j) {
        float h = 0.f;
#pragma unroll
        for (int i = 0; i < 16; ++i) {
            float4 w = ((const float4*)(attW + j * D_EMB))[i];  // uniform -> s_load
            h += w.x * x[i].x + w.y * x[i].y + w.z * x[i].z + w.w * x[i].w;
        }
        beta += attV[j] * tanhf(h);
    }
    ws[WS_EB + tid] = expf(beta);
}

// ---------------------------------------------------------------------------
// Kernel A2: segment accumulation of exp_beta and exp_beta*embed per batch.
// One wave owns a strip of <=25 mentions. The ENTIRE strip's indices and
// exp_beta are preloaded with one per-lane coalesced load each (lane l holds
// mention wstart+l), then broadcast per-mention via __shfl. Inner loop is
// only: 2 shfl + 1 coalesced 256B row load + fma, unrolled x4 so 4 row
// loads are in flight. Register accumulate; flush on (rare, wave-uniform)
// batch change straight to global atomics. Tail lanes carry eb=0 -> zero
// contribution, no guards.
// ---------------------------------------------------------------------------
#define KA2_L 25
__global__ __launch_bounds__(256) void kA2(const float* __restrict__ ge,
                                           const int* __restrict__ mi,
                                           const int* __restrict__ mbi,
                                           float* __restrict__ ws) {
    int lane = threadIdx.x & 63;
    int wave = (blockIdx.x * 256 + threadIdx.x) >> 6;
    int wstart = wave * KA2_L;
    if (wstart >= NMENT) return;
    int wend = min(wstart + KA2_L, NMENT);
    int len  = wend - wstart;

    int idx    = wstart + lane;
    bool valid = idx < wend;
    int lastB  = mbi[wend - 1];
    int nd     = valid ? mi[idx] : 0;
    int bb     = valid ? mbi[idx] : lastB;
    float ebv  = valid ? ws[WS_EB + nd] : 0.f;
    int code   = nd | (bb << 17);          // nd < 2^17, bb < 64

    float acc = 0.f, dacc = 0.f;
    int curb = __shfl(code, 0) >> 17;

    int Lr = (len + 3) & ~3;
    for (int u0 = 0; u0 < Lr; u0 += 4) {
        int   c4[4]; float e4[4]; float x4[4];
#pragma unroll
        for (int j = 0; j < 4; ++j) {
            int u = u0 + j;
            c4[j] = __shfl(code, u);
            e4[j] = __shfl(ebv, u);
            int nd_ = c4[j] & 0x1FFFF;
            x4[j] = ge[(size_t)nd_ * D_EMB + lane];
        }
#pragma unroll
        for (int j = 0; j < 4; ++j) {
            int b = c4[j] >> 17;
            if (b != curb) {               // wave-uniform, rare
                atomicAdd(&ws[WS_NUM + curb * 64 + lane], acc);
                if (lane == 0) atomicAdd(&ws[WS_DEN + curb], dacc);
                acc = 0.f; dacc = 0.f; curb = b;
            }
            acc  = fmaf(e4[j], x4[j], acc);
            dacc += e4[j];
        }
    }
    atomicAdd(&ws[WS_NUM + curb * 64 + lane], acc);
    if (lane == 0) atomicAdd(&ws[WS_DEN + curb], dacc);
}

// ---------------------------------------------------------------------------
// Kernel BW: normalize portrait + compute layer gate weights.
// Grid: 128 blocks = (layer, group); 64 threads (lane d = dim d).
// ---------------------------------------------------------------------------
__global__ __launch_bounds__(64) void kBW(const float* __restrict__ ge,
                                          const float* __restrict__ utter,
                                          const int* __restrict__ grpb,
                                          const int* __restrict__ lastI,
                                          const int* __restrict__ intentI,
                                          const float* __restrict__ W1w,
                                          const float* __restrict__ W1b,
                                          const float* __restrict__ W2w,
                                          const float* __restrict__ W2b,
                                          const float* __restrict__ intentEmb,
                                          float* __restrict__ ws) {
    int bi = blockIdx.x;         // 0..127
    int l  = bi >> 6;
    int g  = bi & 63;
    int d  = threadIdx.x;

    if (l == 0) {
        // write normalized portrait once (batch index == g here)
        ws[WS_PORT + g * 64 + d] = ws[WS_NUM + g * 64 + d] / ws[WS_DEN + g];
    }
    int gb = grpb[bi];
    float pd = ws[WS_NUM + gb * 64 + d] / ws[WS_DEN + gb];

    int last = lastI[bi];
    float gl = (last < N_NODES) ? ge[(size_t)last * D_EMB + d] : 0.f;
    int it = intentI[bi];
    float ie = intentEmb[it * D_EMB + d];

    const float* Ww = (l == 0) ? W1w : W2w;
    float bias      = (l == 0) ? W1b[0] : W2b[0];

    float val = utter[gb * D_EMB + d] * Ww[d]
              + pd * Ww[64 + d]
              + gl * Ww[128 + d]
              + ie * Ww[192 + d];
#pragma unroll
    for (int off = 32; off; off >>= 1) val += __shfl_xor(val, off);
    if (d == 0) ws[WS_W + bi] = 1.f / (1.f + expf(-(val + bias)));
}

// ---------------------------------------------------------------------------
// Kernel C: main scoring. 16 lanes per k (4 k's per wave), 512-thread blocks
// -> 4 blocks/CU, 32 waves/CU. 2*KSEL divisible by 4 -> exact group-stride
// loop, no bounds guard. unroll 2 for 2 gathers in flight per wave.
// out[k] = sum_d (c_u*utter[b][d] + c_p*portrait[b][d]) * graph_e[node][d]
// ---------------------------------------------------------------------------
__global__ __launch_bounds__(512, 8) void kC(const float* __restrict__ ge,
                                             const float* __restrict__ utter,
                                             const int* __restrict__ sel,
                                             const int* __restrict__ selb,
                                             const int* __restrict__ selg,
                                             const float* __restrict__ masks,
                                             const float* __restrict__ ws,
                                             float* __restrict__ out) {
    __shared__ float4 sU[64 * 17];   // utter, f4-stride 17 (dword stride 68)
    __shared__ float4 sP[64 * 17];   // portrait
    __shared__ float  sW[128];       // gate weights

    for (int i = threadIdx.x; i < 64 * 16; i += 512) {
        int r = i >> 4, c = i & 15;
        sU[r * 17 + c] = ((const float4*)utter)[i];
        sP[r * 17 + c] = ((const float4*)(ws + WS_PORT))[i];
    }
    if (threadIdx.x < 128) sW[threadIdx.x] = ws[WS_W + threadIdx.x];
    __syncthreads();

    int lane = threadIdx.x & 63;
    int widb = threadIdx.x >> 6;
    int wave = blockIdx.x * 8 + widb;
    int totalWaves = gridDim.x * 8;
    int grp = lane >> 4;     // which of 4 k's this lane serves
    int lp  = lane & 15;     // position within the k-group (4 dims each)

    const float4* g4 = (const float4*)ge;
    const int NGRP = 2 * KSEL / 4;   // 250000

#pragma unroll 2
    for (int gi = wave; gi < NGRP; gi += totalWaves) {
        int kk = gi * 4 + grp;       // always < 2*KSEL
        int node = sel[kk];
        int b    = selb[kk];
        int g    = selg[kk];
        float cu, cp;
        if (kk < KSEL) {
            float w = sW[g];
            cu = w; cp = 1.f - w;
        } else {
            float mask = masks[kk];
            float lw = sW[b];
            float w1 = sW[64 + g];
            cu = fmaf(mask, w1, lw);
            cp = fmaf(mask, 1.f - w1, 1.f - lw);
        }
        float4 f = make_float4(0.f, 0.f, 0.f, 0.f);
        if (node < N_NODES) f = g4[(size_t)node * 16 + lp];
        float4 tu = sU[b * 17 + lp];
        float4 tp = sP[b * 17 + lp];
        float val = (cu * tu.x + cp * tp.x) * f.x
                  + (cu * tu.y + cp * tp.y) * f.y
                  + (cu * tu.z + cp * tp.z) * f.z
                  + (cu * tu.w + cp * tp.w) * f.w;
        val += __shfl_xor(val, 1);
        val += __shfl_xor(val, 2);
        val += __shfl_xor(val, 4);
        val += __shfl_xor(val, 8);
        if (lp == 0) out[kk] = val;
    }
}

extern "C" void kernel_launch(void* const* d_in, const int* in_sizes, int n_in,
                              void* d_out, int out_size, void* d_ws, size_t ws_size,
                              hipStream_t stream) {
    const float* ge        = (const float*)d_in[0];
    const float* utter     = (const float*)d_in[1];
    const int*   mi        = (const int*)d_in[2];
    const int*   mbi       = (const int*)d_in[3];
    const int*   sel       = (const int*)d_in[4];
    const int*   selb      = (const int*)d_in[5];
    const int*   selg      = (const int*)d_in[6];
    const int*   grpb      = (const int*)d_in[7];
    const int*   lastI     = (const int*)d_in[8];
    const int*   intentI   = (const int*)d_in[9];
    const float* masks     = (const float*)d_in[10];
    const float* attW      = (const float*)d_in[11];
    const float* attV      = (const float*)d_in[12];
    const float* W1w       = (const float*)d_in[13];
    const float* W1b       = (const float*)d_in[14];
    const float* W2w       = (const float*)d_in[15];
    const float* W2b       = (const float*)d_in[16];
    const float* intentEmb = (const float*)d_in[17];
    float* ws  = (float*)d_ws;
    float* out = (float*)d_out;

    int ka2_waves  = (NMENT + KA2_L - 1) / KA2_L;          // 8000
    int ka2_blocks = (ka2_waves + 3) / 4;                  // 2000

    kP <<<dim3((N_NODES + 255) / 256), dim3(256), 0, stream>>>(ge, attW, attV, ws);
    kA2<<<dim3(ka2_blocks), dim3(256), 0, stream>>>(ge, mi, mbi, ws);
    kBW<<<dim3(128), dim3(64), 0, stream>>>(ge, utter, grpb, lastI, intentI,
                                            W1w, W1b, W2w, W2b, intentEmb, ws);
    kC <<<dim3(2048), dim3(512), 0, stream>>>(ge, utter, sel, selb, selg, masks, ws, out);
}

// Round 7
// 114.110 us; speedup vs baseline: 1.3889x; 1.0537x over previous
//
#include <hip/hip_runtime.h>
#include <math.h>

#define N_NODES 100000
#define D_EMB   64
#define KSEL    500000
#define NMENT   200000
#define ATT_H   20

// ws layout (float offsets)
#define WS_EB    0          // [100000]  per-node exp(beta)
#define WS_NUM   100000     // [64*64]   portrait numerator (atomic accum)
#define WS_DEN   104096     // [64]      portrait denominator
#define WS_PORT  104160     // [64*64]   normalized portrait
#define WS_W     108256     // [2*64]    layer weights (sigmoid)
#define WS_BF_FLOAT_OFF 108416                    // 256B-aligned byte 433664
#define WS_BF_BYTE ((size_t)WS_BF_FLOAT_OFF * 4)
#define BF_TABLE_BYTES ((size_t)N_NODES * 128)    // 100000 rows x 64 bf16

__device__ __forceinline__ unsigned pack2bf(float a, float b) {
    unsigned ua = __float_as_uint(a), ub = __float_as_uint(b);
    ua = (ua + 0x7FFFu + ((ua >> 16) & 1u)) >> 16;   // RNE bf16
    ub = (ub + 0x7FFFu + ((ub >> 16) & 1u)) >> 16;
    return ua | (ub << 16);
}

// ---------------------------------------------------------------------------
// Kernel P: per-node attention potential eb[n] = exp(tanh(ge[n] @ Wt) @ V).
// Also zeroes num/den accumulators and (PACK) writes the bf16 row table —
// kP already reads every row, so the pack is nearly free.
// ---------------------------------------------------------------------------
template<bool PACK>
__global__ __launch_bounds__(256) void kP(const float* __restrict__ ge,
                                          const float* __restrict__ attW,
                                          const float* __restrict__ attV,
                                          float* __restrict__ ws) {
    int tid = blockIdx.x * 256 + threadIdx.x;
    if (tid < 64 * 64 + 64) ws[WS_NUM + tid] = 0.f;   // zero num + den
    if (tid >= N_NODES) return;

    const float4* g4 = (const float4*)(ge + (size_t)tid * D_EMB);
    float4 x[16];
#pragma unroll
    for (int i = 0; i < 16; ++i) x[i] = g4[i];

    if constexpr (PACK) {
        uint4* dst = (uint4*)((char*)ws + WS_BF_BYTE + (size_t)tid * 128);
#pragma unroll
        for (int j = 0; j < 8; ++j) {
            uint4 o;
            o.x = pack2bf(x[2*j].x,   x[2*j].y);
            o.y = pack2bf(x[2*j].z,   x[2*j].w);
            o.z = pack2bf(x[2*j+1].x, x[2*j+1].y);
            o.w = pack2bf(x[2*j+1].z, x[2*j+1].w);
            dst[j] = o;
        }
    }

    float beta = 0.f;
#pragma unroll
    for (int j = 0; j < ATT_H; ++j) {
        float h = 0.f;
#pragma unroll
        for (int i = 0; i < 16; ++i) {
            float4 w = ((const float4*)(attW + j * D_EMB))[i];  // uniform -> s_load
            h += w.x * x[i].x + w.y * x[i].y + w.z * x[i].z + w.w * x[i].w;
        }
        beta += attV[j] * tanhf(h);
    }
    ws[WS_EB + tid] = expf(beta);
}

// ---------------------------------------------------------------------------
// Kernel A2: segment accumulation of exp_beta and exp_beta*embed per batch.
// Strip preload + __shfl broadcast, x4 unrolled row gathers in flight.
// ---------------------------------------------------------------------------
#define KA2_L 25
__global__ __launch_bounds__(256) void kA2(const float* __restrict__ ge,
                                           const int* __restrict__ mi,
                                           const int* __restrict__ mbi,
                                           float* __restrict__ ws) {
    int lane = threadIdx.x & 63;
    int wave = (blockIdx.x * 256 + threadIdx.x) >> 6;
    int wstart = wave * KA2_L;
    if (wstart >= NMENT) return;
    int wend = min(wstart + KA2_L, NMENT);
    int len  = wend - wstart;

    int idx    = wstart + lane;
    bool valid = idx < wend;
    int lastB  = mbi[wend - 1];
    int nd     = valid ? mi[idx] : 0;
    int bb     = valid ? mbi[idx] : lastB;
    float ebv  = valid ? ws[WS_EB + nd] : 0.f;
    int code   = nd | (bb << 17);          // nd < 2^17, bb < 64

    float acc = 0.f, dacc = 0.f;
    int curb = __shfl(code, 0) >> 17;

    int Lr = (len + 3) & ~3;
    for (int u0 = 0; u0 < Lr; u0 += 4) {
        int   c4[4]; float e4[4]; float x4[4];
#pragma unroll
        for (int j = 0; j < 4; ++j) {
            int u = u0 + j;
            c4[j] = __shfl(code, u);
            e4[j] = __shfl(ebv, u);
            int nd_ = c4[j] & 0x1FFFF;
            x4[j] = ge[(size_t)nd_ * D_EMB + lane];
        }
#pragma unroll
        for (int j = 0; j < 4; ++j) {
            int b = c4[j] >> 17;
            if (b != curb) {               // wave-uniform, rare
                atomicAdd(&ws[WS_NUM + curb * 64 + lane], acc);
                if (lane == 0) atomicAdd(&ws[WS_DEN + curb], dacc);
                acc = 0.f; dacc = 0.f; curb = b;
            }
            acc  = fmaf(e4[j], x4[j], acc);
            dacc += e4[j];
        }
    }
    atomicAdd(&ws[WS_NUM + curb * 64 + lane], acc);
    if (lane == 0) atomicAdd(&ws[WS_DEN + curb], dacc);
}

// ---------------------------------------------------------------------------
// Kernel BW: normalize portrait + compute layer gate weights.
// ---------------------------------------------------------------------------
__global__ __launch_bounds__(64) void kBW(const float* __restrict__ ge,
                                          const float* __restrict__ utter,
                                          const int* __restrict__ grpb,
                                          const int* __restrict__ lastI,
                                          const int* __restrict__ intentI,
                                          const float* __restrict__ W1w,
                                          const float* __restrict__ W1b,
                                          const float* __restrict__ W2w,
                                          const float* __restrict__ W2b,
                                          const float* __restrict__ intentEmb,
                                          float* __restrict__ ws) {
    int bi = blockIdx.x;         // 0..127
    int l  = bi >> 6;
    int g  = bi & 63;
    int d  = threadIdx.x;

    if (l == 0) {
        ws[WS_PORT + g * 64 + d] = ws[WS_NUM + g * 64 + d] / ws[WS_DEN + g];
    }
    int gb = grpb[bi];
    float pd = ws[WS_NUM + gb * 64 + d] / ws[WS_DEN + gb];

    int last = lastI[bi];
    float gl = (last < N_NODES) ? ge[(size_t)last * D_EMB + d] : 0.f;
    int it = intentI[bi];
    float ie = intentEmb[it * D_EMB + d];

    const float* Ww = (l == 0) ? W1w : W2w;
    float bias      = (l == 0) ? W1b[0] : W2b[0];

    float val = utter[gb * D_EMB + d] * Ww[d]
              + pd * Ww[64 + d]
              + gl * Ww[128 + d]
              + ie * Ww[192 + d];
#pragma unroll
    for (int off = 32; off; off >>= 1) val += __shfl_xor(val, off);
    if (d == 0) ws[WS_W + bi] = 1.f / (1.f + expf(-(val + bias)));
}

// ---------------------------------------------------------------------------
// Kernel C: main scoring, explicitly software-pipelined 3 stages deep:
//   stage I: index loads for gi+2W;  stage R: row gather for gi+W;
//   stage C: compute/reduce/store for gi.  Guarantees 2 row gathers +
// 4-8 index loads in flight per wave (round-6 showed the compiler kept
// VGPR=16 and did not pipeline on its own).
// BF16 variant reads the 128B bf16 rows packed by kP (half the bytes).
// ---------------------------------------------------------------------------
template<bool BF16>
__global__ __launch_bounds__(512, 8) void kC(const float* __restrict__ ge,
                                             const float* __restrict__ utter,
                                             const int* __restrict__ sel,
                                             const int* __restrict__ selb,
                                             const int* __restrict__ selg,
                                             const float* __restrict__ masks,
                                             const float* __restrict__ ws,
                                             float* __restrict__ out) {
    __shared__ float4 sU[64 * 17];   // f4-stride 17 breaks bank aliasing
    __shared__ float4 sP[64 * 17];
    __shared__ float  sW[128];

    for (int i = threadIdx.x; i < 64 * 16; i += 512) {
        int r = i >> 4, c = i & 15;
        sU[r * 17 + c] = ((const float4*)utter)[i];
        sP[r * 17 + c] = ((const float4*)(ws + WS_PORT))[i];
    }
    if (threadIdx.x < 128) sW[threadIdx.x] = ws[WS_W + threadIdx.x];
    __syncthreads();

    int lane = threadIdx.x & 63;
    int wave = blockIdx.x * 8 + (threadIdx.x >> 6);
    const int W = gridDim.x * 8;
    int grp = lane >> 4;     // which of 4 k's this lane serves
    int lp  = lane & 15;     // position within the k-group (4 dims each)

    const unsigned short* bft = (const unsigned short*)((const char*)ws + WS_BF_BYTE);
    const float4* g4 = (const float4*)ge;
    const int NGRP = 2 * KSEL / 4;   // 250000

    int giA = wave, giB = wave + W, giC = wave + 2 * W;
    bool vA = giA < NGRP, vB = giB < NGRP;

    int nA = 0, bA = 0, gA = 0; float mA = 0.f;
    int nB = 0, bB = 0, gB = 0; float mB = 0.f;
    if (vA) { int kk = giA * 4 + grp; nA = sel[kk]; bA = selb[kk]; gA = selg[kk]; mA = masks[kk]; }
    if (vB) { int kk = giB * 4 + grp; nB = sel[kk]; bB = selb[kk]; gB = selg[kk]; mB = masks[kk]; }

    uint2  rA2 = make_uint2(0u, 0u);
    float4 rA4 = make_float4(0.f, 0.f, 0.f, 0.f);
    if (vA) {
        if constexpr (BF16) { if (nA < N_NODES) rA2 = *(const uint2*)(bft + (size_t)nA * 64 + lp * 4); }
        else                { if (nA < N_NODES) rA4 = g4[(size_t)nA * 16 + lp]; }
    }

    while (vA) {
        bool vC = giC < NGRP;
        int nC = 0, bC = 0, gC = 0; float mC = 0.f;
        if (vC) { int kk = giC * 4 + grp; nC = sel[kk]; bC = selb[kk]; gC = selg[kk]; mC = masks[kk]; }

        uint2  rB2 = rA2;
        float4 rB4 = rA4;
        if (vB) {
            rB2 = make_uint2(0u, 0u); rB4 = make_float4(0.f, 0.f, 0.f, 0.f);
            if constexpr (BF16) { if (nB < N_NODES) rB2 = *(const uint2*)(bft + (size_t)nB * 64 + lp * 4); }
            else                { if (nB < N_NODES) rB4 = g4[(size_t)nB * 16 + lp]; }
        }

        // compute gi A
        int kkA = giA * 4 + grp;
        float cu, cp;
        if (kkA < KSEL) {                       // wave-uniform (KSEL%4==0)
            float w = sW[gA]; cu = w; cp = 1.f - w;
        } else {
            float lw = sW[bA]; float w1 = sW[64 + gA];
            cu = fmaf(mA, w1, lw);
            cp = fmaf(mA, 1.f - w1, 1.f - lw);
        }
        float f0, f1, f2, f3;
        if constexpr (BF16) {
            f0 = __uint_as_float(rA2.x << 16);
            f1 = __uint_as_float(rA2.x & 0xFFFF0000u);
            f2 = __uint_as_float(rA2.y << 16);
            f3 = __uint_as_float(rA2.y & 0xFFFF0000u);
        } else { f0 = rA4.x; f1 = rA4.y; f2 = rA4.z; f3 = rA4.w; }
        float4 tu = sU[bA * 17 + lp];
        float4 tp = sP[bA * 17 + lp];
        float val = (cu * tu.x + cp * tp.x) * f0
                  + (cu * tu.y + cp * tp.y) * f1
                  + (cu * tu.z + cp * tp.z) * f2
                  + (cu * tu.w + cp * tp.w) * f3;
        val += __shfl_xor(val, 1);
        val += __shfl_xor(val, 2);
        val += __shfl_xor(val, 4);
        val += __shfl_xor(val, 8);
        if (lp == 0) out[kkA] = val;

        // rotate pipeline
        nA = nB; bA = bB; gA = gB; mA = mB;
        nB = nC; bB = bC; gB = gC; mB = mC;
        rA2 = rB2; rA4 = rB4;
        giA = giB; vA = vB; giB = giC; vB = vC; giC += W;
    }
}

extern "C" void kernel_launch(void* const* d_in, const int* in_sizes, int n_in,
                              void* d_out, int out_size, void* d_ws, size_t ws_size,
                              hipStream_t stream) {
    const float* ge        = (const float*)d_in[0];
    const float* utter     = (const float*)d_in[1];
    const int*   mi        = (const int*)d_in[2];
    const int*   mbi       = (const int*)d_in[3];
    const int*   sel       = (const int*)d_in[4];
    const int*   selb      = (const int*)d_in[5];
    const int*   selg      = (const int*)d_in[6];
    const int*   grpb      = (const int*)d_in[7];
    const int*   lastI     = (const int*)d_in[8];
    const int*   intentI   = (const int*)d_in[9];
    const float* masks     = (const float*)d_in[10];
    const float* attW      = (const float*)d_in[11];
    const float* attV      = (const float*)d_in[12];
    const float* W1w       = (const float*)d_in[13];
    const float* W1b       = (const float*)d_in[14];
    const float* W2w       = (const float*)d_in[15];
    const float* W2b       = (const float*)d_in[16];
    const float* intentEmb = (const float*)d_in[17];
    float* ws  = (float*)d_ws;
    float* out = (float*)d_out;

    bool useBf = ws_size >= WS_BF_BYTE + BF_TABLE_BYTES;

    int ka2_waves  = (NMENT + KA2_L - 1) / KA2_L;          // 8000
    int ka2_blocks = (ka2_waves + 3) / 4;                  // 2000

    if (useBf)
        kP<true><<<dim3((N_NODES + 255) / 256), dim3(256), 0, stream>>>(ge, attW, attV, ws);
    else
        kP<false><<<dim3((N_NODES + 255) / 256), dim3(256), 0, stream>>>(ge, attW, attV, ws);

    kA2<<<dim3(ka2_blocks), dim3(256), 0, stream>>>(ge, mi, mbi, ws);
    kBW<<<dim3(128), dim3(64), 0, stream>>>(ge, utter, grpb, lastI, intentI,
                                            W1w, W1b, W2w, W2b, intentEmb, ws);

    if (useBf)
        kC<true><<<dim3(1024), dim3(512), 0, stream>>>(ge, utter, sel, selb, selg, masks, ws, out);
    else
        kC<false><<<dim3(1024), dim3(512), 0, stream>>>(ge, utter, sel, selb, selg, masks, ws, out);
}

// Round 8
// 79.884 us; speedup vs baseline: 1.9840x; 1.4284x over previous
//
#include <hip/hip_runtime.h>
#include <math.h>

#define N_NODES 100000
#define D_EMB   64
#define KSEL    500000
#define NMENT   200000
#define ATT_H   20

// ws layout (float offsets)
#define WS_EB    0                 // [100000] per-node exp(beta)
#define WS_NUM   100000            // [64*64]  portrait numerator
#define WS_DEN   104096            // [64]     portrait denominator
#define WS_PORT  104160            // [64*64]  normalized portrait
#define WS_W     108256            // [2*64]   gate weights
#define WS_KCODE 108384            // [1000000] int: sel | b<<17 | g<<23
#define WS_MCODE 1108384           // [200000]  int: mi | b<<17
#define WS_BF_FLOAT_OFF 1308416    // bf16 row table (16B aligned)
#define WS_BF_BYTE ((size_t)WS_BF_FLOAT_OFF * 4)
#define WS_TOTAL_BYTES ((size_t)(WS_BF_FLOAT_OFF + N_NODES * 32) * 4)

#define NPB 391    // node blocks in kP
#define MCB 196    // mcode packer blocks
#define KCB 977    // kcode packer blocks

__device__ __forceinline__ unsigned pack2bf(float a, float b) {
    unsigned ua = __float_as_uint(a), ub = __float_as_uint(b);
    ua = (ua + 0x7FFFu + ((ua >> 16) & 1u)) >> 16;   // RNE bf16
    ub = (ub + 0x7FFFu + ((ub >> 16) & 1u)) >> 16;
    return ua | (ub << 16);
}
__device__ __forceinline__ float uasf(unsigned u) { return __uint_as_float(u); }

// ---------------------------------------------------------------------------
// Kernel P (fused): blocks [0,NPB): per-node eb + bf16 row pack + accum zero.
// blocks [NPB,NPB+MCB): pack mcode. blocks [NPB+MCB,..+KCB): pack kcode.
// ---------------------------------------------------------------------------
template<bool PACK>
__global__ __launch_bounds__(256) void kP(const float* __restrict__ ge,
                                          const float* __restrict__ attW,
                                          const float* __restrict__ attV,
                                          const int* __restrict__ mi,
                                          const int* __restrict__ mbi,
                                          const int* __restrict__ sel,
                                          const int* __restrict__ selb,
                                          const int* __restrict__ selg,
                                          float* __restrict__ ws) {
    int bid = blockIdx.x;
    if (PACK && bid >= NPB) {
        int t = threadIdx.x;
        if (bid < NPB + MCB) {
            int base = (bid - NPB) * 1024 + t * 4;
            int* mc = (int*)ws + WS_MCODE;
            if (base + 3 < NMENT) {
                int4 a = *(const int4*)(mi + base);
                int4 b = *(const int4*)(mbi + base);
                int4 o;
                o.x = a.x | (b.x << 17); o.y = a.y | (b.y << 17);
                o.z = a.z | (b.z << 17); o.w = a.w | (b.w << 17);
                *(int4*)(mc + base) = o;
            } else {
                for (int i = base; i < NMENT; ++i) mc[i] = mi[i] | (mbi[i] << 17);
            }
        } else {
            int base = (bid - NPB - MCB) * 1024 + t * 4;
            int* kc = (int*)ws + WS_KCODE;
            if (base + 3 < 2 * KSEL) {
                int4 a = *(const int4*)(sel + base);
                int4 b = *(const int4*)(selb + base);
                int4 g = *(const int4*)(selg + base);
                int4 o;
                o.x = a.x | (b.x << 17) | (g.x << 23);
                o.y = a.y | (b.y << 17) | (g.y << 23);
                o.z = a.z | (b.z << 17) | (g.z << 23);
                o.w = a.w | (b.w << 17) | (g.w << 23);
                *(int4*)(kc + base) = o;
            } else {
                for (int i = base; i < 2 * KSEL; ++i)
                    kc[i] = sel[i] | (selb[i] << 17) | (selg[i] << 23);
            }
        }
        return;
    }

    int tid = bid * 256 + threadIdx.x;
    if (tid < 64 * 64 + 64) ws[WS_NUM + tid] = 0.f;   // zero num + den
    if (tid >= N_NODES) return;

    const float4* g4 = (const float4*)(ge + (size_t)tid * D_EMB);
    float4 x[16];
#pragma unroll
    for (int i = 0; i < 16; ++i) x[i] = g4[i];

    if constexpr (PACK) {
        uint4* dst = (uint4*)((char*)ws + WS_BF_BYTE + (size_t)tid * 128);
#pragma unroll
        for (int j = 0; j < 8; ++j) {
            uint4 o;
            o.x = pack2bf(x[2*j].x,   x[2*j].y);
            o.y = pack2bf(x[2*j].z,   x[2*j].w);
            o.z = pack2bf(x[2*j+1].x, x[2*j+1].y);
            o.w = pack2bf(x[2*j+1].z, x[2*j+1].w);
            dst[j] = o;
        }
    }

    float beta = 0.f;
#pragma unroll
    for (int j = 0; j < ATT_H; ++j) {
        float h = 0.f;
#pragma unroll
        for (int i = 0; i < 16; ++i) {
            float4 w = ((const float4*)(attW + j * D_EMB))[i];
            h += w.x * x[i].x + w.y * x[i].y + w.z * x[i].z + w.w * x[i].w;
        }
        beta += attV[j] * tanhf(h);
    }
    ws[WS_EB + tid] = expf(beta);
}

// ---------------------------------------------------------------------------
// Kernel A2 (new): 2000 blocks x 4 waves; each wave owns exactly 25 mentions.
// 16 lanes per mention (bf16 row chunk uint2 per lane). Fully-unrolled
// 7-iteration pipeline: all 7 codes loaded, then all 7 eb + 7 rows in flight.
// Register acc per group, flush-on-batch-change to per-block LDS accumulator
// (ds_add_f32), one small global flush per block.
// ---------------------------------------------------------------------------
__global__ __launch_bounds__(256, 8) void kA2n(float* __restrict__ ws) {
    __shared__ float lacc[64 * 64];
    __shared__ float lden[64];
    for (int i = threadIdx.x; i < 64 * 64; i += 256) lacc[i] = 0.f;
    if (threadIdx.x < 64) lden[threadIdx.x] = 0.f;
    __syncthreads();

    const int* mc = (const int*)ws + WS_MCODE;
    const unsigned short* bft = (const unsigned short*)((const char*)ws + WS_BF_BYTE);

    int lane = threadIdx.x & 63;
    int grp  = lane >> 4, lp = lane & 15;
    int wave = blockIdx.x * 4 + (threadIdx.x >> 6);
    int s = wave * 25;                       // 8000 waves x 25 = 200000 exactly

    int cd[7]; float ebv[7]; uint2 rr[7];
#pragma unroll
    for (int i = 0; i < 7; ++i) {
        bool v = (4 * i + grp) < 25;
        cd[i] = v ? mc[s + 4 * i + grp] : 0;
    }
#pragma unroll
    for (int i = 0; i < 7; ++i) {
        bool v = (4 * i + grp) < 25;
        int nd = cd[i] & 0x1FFFF;
        ebv[i] = v ? ws[WS_EB + nd] : 0.f;
        rr[i]  = *(const uint2*)(bft + (size_t)nd * 64 + lp * 4);
    }

    int curb = (cd[0] >> 17) & 63;
    float4 acc = make_float4(0.f, 0.f, 0.f, 0.f);
    float dacc = 0.f;
#pragma unroll
    for (int i = 0; i < 7; ++i) {
        int b = (cd[i] >> 17) & 63;
        bool v = (4 * i + grp) < 25;
        if (v && b != curb) {                // group-uniform, rare
            atomicAdd(&lacc[curb * 64 + lp * 4 + 0], acc.x);
            atomicAdd(&lacc[curb * 64 + lp * 4 + 1], acc.y);
            atomicAdd(&lacc[curb * 64 + lp * 4 + 2], acc.z);
            atomicAdd(&lacc[curb * 64 + lp * 4 + 3], acc.w);
            if (lp == 0) atomicAdd(&lden[curb], dacc);
            acc = make_float4(0.f, 0.f, 0.f, 0.f); dacc = 0.f; curb = b;
        }
        float e = ebv[i];
        acc.x = fmaf(e, uasf(rr[i].x << 16),         acc.x);
        acc.y = fmaf(e, uasf(rr[i].x & 0xFFFF0000u), acc.y);
        acc.z = fmaf(e, uasf(rr[i].y << 16),         acc.z);
        acc.w = fmaf(e, uasf(rr[i].y & 0xFFFF0000u), acc.w);
        dacc += e;
    }
    atomicAdd(&lacc[curb * 64 + lp * 4 + 0], acc.x);
    atomicAdd(&lacc[curb * 64 + lp * 4 + 1], acc.y);
    atomicAdd(&lacc[curb * 64 + lp * 4 + 2], acc.z);
    atomicAdd(&lacc[curb * 64 + lp * 4 + 3], acc.w);
    if (lp == 0) atomicAdd(&lden[curb], dacc);
    __syncthreads();

    // block-level flush: strip covers batches [b0, b1] (sorted mbi)
    int sB = blockIdx.x * 100;               // 2000 blocks x 100 = 200000
    int b0 = (mc[sB] >> 17) & 63;
    int b1 = (mc[sB + 99] >> 17) & 63;
    int nb = b1 - b0 + 1;
    for (int idx = threadIdx.x; idx < nb * 64; idx += 256) {
        int bb = b0 + (idx >> 6), d = idx & 63;
        float v = lacc[bb * 64 + d];
        if (v != 0.f) atomicAdd(&ws[WS_NUM + bb * 64 + d], v);
    }
    if (threadIdx.x < nb) {
        float v = lden[b0 + threadIdx.x];
        if (v != 0.f) atomicAdd(&ws[WS_DEN + b0 + threadIdx.x], v);
    }
}

// ---------------------------------------------------------------------------
// Kernel BW: normalize portrait + compute layer gate weights.
// ---------------------------------------------------------------------------
__global__ __launch_bounds__(64) void kBW(const float* __restrict__ ge,
                                          const float* __restrict__ utter,
                                          const int* __restrict__ grpb,
                                          const int* __restrict__ lastI,
                                          const int* __restrict__ intentI,
                                          const float* __restrict__ W1w,
                                          const float* __restrict__ W1b,
                                          const float* __restrict__ W2w,
                                          const float* __restrict__ W2b,
                                          const float* __restrict__ intentEmb,
                                          float* __restrict__ ws) {
    int bi = blockIdx.x;         // 0..127
    int l  = bi >> 6;
    int g  = bi & 63;
    int d  = threadIdx.x;

    if (l == 0) {
        ws[WS_PORT + g * 64 + d] = ws[WS_NUM + g * 64 + d] / ws[WS_DEN + g];
    }
    int gb = grpb[bi];
    float pd = ws[WS_NUM + gb * 64 + d] / ws[WS_DEN + gb];

    int last = lastI[bi];
    float gl = (last < N_NODES) ? ge[(size_t)last * D_EMB + d] : 0.f;
    int it = intentI[bi];
    float ie = intentEmb[it * D_EMB + d];

    const float* Ww = (l == 0) ? W1w : W2w;
    float bias      = (l == 0) ? W1b[0] : W2b[0];

    float val = utter[gb * D_EMB + d] * Ww[d]
              + pd * Ww[64 + d]
              + gl * Ww[128 + d]
              + ie * Ww[192 + d];
#pragma unroll
    for (int off = 32; off; off >>= 1) val += __shfl_xor(val, off);
    if (d == 0) ws[WS_W + bi] = 1.f / (1.f + expf(-(val + bias)));
}

// ---------------------------------------------------------------------------
// Kernel C (new): 8 lanes per k (8 k's per wave-iteration), bf16 rows as
// uint4 (16B/lane), packed codes (1 load/k), masks only for layer-2 gi.
// 4-slot rotation: 2 codes + 2 rows in flight per wave.
// ---------------------------------------------------------------------------
__global__ __launch_bounds__(512, 8) void kCn(const float* __restrict__ utter,
                                              const float* __restrict__ masks,
                                              const float* __restrict__ ws,
                                              float* __restrict__ out) {
    __shared__ float4 sU[64 * 17];
    __shared__ float4 sP[64 * 17];
    __shared__ float  sWd[128];

    for (int i = threadIdx.x; i < 64 * 16; i += 512) {
        int r = i >> 4, c = i & 15;
        sU[r * 17 + c] = ((const float4*)utter)[i];
        sP[r * 17 + c] = ((const float4*)(ws + WS_PORT))[i];
    }
    if (threadIdx.x < 128) sWd[threadIdx.x] = ws[WS_W + threadIdx.x];
    __syncthreads();

    int lane = threadIdx.x & 63;
    int wave = blockIdx.x * 8 + (threadIdx.x >> 6);
    const int W = gridDim.x * 8;
    int grp = lane >> 3;     // 8 k's per wave-iteration
    int lp  = lane & 7;      // 16B (8 bf16 dims) per lane

    const int* kc = (const int*)ws + WS_KCODE;
    const unsigned short* bft = (const unsigned short*)((const char*)ws + WS_BF_BYTE);
    const int NGRP = 2 * KSEL / 8;   // 125000
    const int L2G  = KSEL / 8;       // 62500: layer-2 boundary (wave-uniform)

#define LDC(GI, CD, MK) { int gi_ = (GI); bool v_ = gi_ < NGRP; int kk_ = gi_ * 8 + grp; \
        CD = v_ ? kc[kk_] : N_NODES; \
        MK = (v_ && gi_ >= L2G) ? masks[kk_] : 0.f; }
#define LDR(CD, R) { int nd_ = (CD) & 0x1FFFF; \
        R = make_uint4(0u, 0u, 0u, 0u); \
        if (nd_ < N_NODES) R = *(const uint4*)(bft + (size_t)nd_ * 64 + lp * 8); }

    int cd0, cd1, cd2, cd3; float mk0, mk1, mk2, mk3;
    uint4 R0, R1, R2;
    LDC(wave,         cd0, mk0);
    LDC(wave + W,     cd1, mk1);
    LDC(wave + 2 * W, cd2, mk2);
    LDR(cd0, R0);
    LDR(cd1, R1);

    for (int gi = wave; gi < NGRP; gi += W) {
        LDR(cd2, R2);
        LDC(gi + 3 * W, cd3, mk3);

        int b = (cd0 >> 17) & 63;
        int g = (cd0 >> 23) & 63;
        float cu, cp;
        if (gi < L2G) {
            float w = sWd[g]; cu = w; cp = 1.f - w;
        } else {
            float lw = sWd[b]; float w1 = sWd[64 + g];
            cu = fmaf(mk0, w1, lw);
            cp = fmaf(mk0, 1.f - w1, 1.f - lw);
        }
        float4 tu0 = sU[b * 17 + 2 * lp], tu1 = sU[b * 17 + 2 * lp + 1];
        float4 tp0 = sP[b * 17 + 2 * lp], tp1 = sP[b * 17 + 2 * lp + 1];
        float f, val;
        f = uasf(R0.x << 16);         val  = (cu * tu0.x + cp * tp0.x) * f;
        f = uasf(R0.x & 0xFFFF0000u); val += (cu * tu0.y + cp * tp0.y) * f;
        f = uasf(R0.y << 16);         val += (cu * tu0.z + cp * tp0.z) * f;
        f = uasf(R0.y & 0xFFFF0000u); val += (cu * tu0.w + cp * tp0.w) * f;
        f = uasf(R0.z << 16);         val += (cu * tu1.x + cp * tp1.x) * f;
        f = uasf(R0.z & 0xFFFF0000u); val += (cu * tu1.y + cp * tp1.y) * f;
        f = uasf(R0.w << 16);         val += (cu * tu1.z + cp * tp1.z) * f;
        f = uasf(R0.w & 0xFFFF0000u); val += (cu * tu1.w + cp * tp1.w) * f;
        val += __shfl_xor(val, 1);
        val += __shfl_xor(val, 2);
        val += __shfl_xor(val, 4);
        if (lp == 0) out[gi * 8 + grp] = val;

        cd0 = cd1; mk0 = mk1; cd1 = cd2; mk1 = mk2; cd2 = cd3; mk2 = mk3;
        R0 = R1; R1 = R2;
    }
#undef LDC
#undef LDR
}

// ---------------------------------------------------------------------------
// Fallback kernels (ws too small for tables): round-7 proven versions.
// ---------------------------------------------------------------------------
#define KA2_L 25
__global__ __launch_bounds__(256) void kA2_fb(const float* __restrict__ ge,
                                              const int* __restrict__ mi,
                                              const int* __restrict__ mbi,
                                              float* __restrict__ ws) {
    int lane = threadIdx.x & 63;
    int wave = (blockIdx.x * 256 + threadIdx.x) >> 6;
    int wstart = wave * KA2_L;
    if (wstart >= NMENT) return;
    int wend = min(wstart + KA2_L, NMENT);
    int len  = wend - wstart;

    int idx    = wstart + lane;
    bool valid = idx < wend;
    int lastB  = mbi[wend - 1];
    int nd     = valid ? mi[idx] : 0;
    int bb     = valid ? mbi[idx] : lastB;
    float ebv  = valid ? ws[WS_EB + nd] : 0.f;
    int code   = nd | (bb << 17);

    float acc = 0.f, dacc = 0.f;
    int curb = __shfl(code, 0) >> 17;

    int Lr = (len + 3) & ~3;
    for (int u0 = 0; u0 < Lr; u0 += 4) {
        int c4[4]; float e4[4]; float x4[4];
#pragma unroll
        for (int j = 0; j < 4; ++j) {
            int u = u0 + j;
            c4[j] = __shfl(code, u);
            e4[j] = __shfl(ebv, u);
            x4[j] = ge[(size_t)(c4[j] & 0x1FFFF) * D_EMB + lane];
        }
#pragma unroll
        for (int j = 0; j < 4; ++j) {
            int b = c4[j] >> 17;
            if (b != curb) {
                atomicAdd(&ws[WS_NUM + curb * 64 + lane], acc);
                if (lane == 0) atomicAdd(&ws[WS_DEN + curb], dacc);
                acc = 0.f; dacc = 0.f; curb = b;
            }
            acc  = fmaf(e4[j], x4[j], acc);
            dacc += e4[j];
        }
    }
    atomicAdd(&ws[WS_NUM + curb * 64 + lane], acc);
    if (lane == 0) atomicAdd(&ws[WS_DEN + curb], dacc);
}

__global__ __launch_bounds__(512, 8) void kC_fb(const float* __restrict__ ge,
                                                const float* __restrict__ utter,
                                                const int* __restrict__ sel,
                                                const int* __restrict__ selb,
                                                const int* __restrict__ selg,
                                                const float* __restrict__ masks,
                                                const float* __restrict__ ws,
                                                float* __restrict__ out) {
    __shared__ float4 sU[64 * 17];
    __shared__ float4 sP[64 * 17];
    __shared__ float  sW[128];
    for (int i = threadIdx.x; i < 64 * 16; i += 512) {
        int r = i >> 4, c = i & 15;
        sU[r * 17 + c] = ((const float4*)utter)[i];
        sP[r * 17 + c] = ((const float4*)(ws + WS_PORT))[i];
    }
    if (threadIdx.x < 128) sW[threadIdx.x] = ws[WS_W + threadIdx.x];
    __syncthreads();

    int lane = threadIdx.x & 63;
    int wave = blockIdx.x * 8 + (threadIdx.x >> 6);
    int W = gridDim.x * 8;
    int grp = lane >> 4, lp = lane & 15;
    const float4* g4 = (const float4*)ge;
    const int NGRP = 2 * KSEL / 4;

    for (int gi = wave; gi < NGRP; gi += W) {
        int kk = gi * 4 + grp;
        int node = sel[kk], b = selb[kk], g = selg[kk];
        float cu, cp;
        if (kk < KSEL) { float w = sW[g]; cu = w; cp = 1.f - w; }
        else {
            float mask = masks[kk]; float lw = sW[b]; float w1 = sW[64 + g];
            cu = fmaf(mask, w1, lw); cp = fmaf(mask, 1.f - w1, 1.f - lw);
        }
        float4 f = make_float4(0.f, 0.f, 0.f, 0.f);
        if (node < N_NODES) f = g4[(size_t)node * 16 + lp];
        float4 tu = sU[b * 17 + lp];
        float4 tp = sP[b * 17 + lp];
        float val = (cu * tu.x + cp * tp.x) * f.x
                  + (cu * tu.y + cp * tp.y) * f.y
                  + (cu * tu.z + cp * tp.z) * f.z
                  + (cu * tu.w + cp * tp.w) * f.w;
        val += __shfl_xor(val, 1);
        val += __shfl_xor(val, 2);
        val += __shfl_xor(val, 4);
        val += __shfl_xor(val, 8);
        if (lp == 0) out[kk] = val;
    }
}

extern "C" void kernel_launch(void* const* d_in, const int* in_sizes, int n_in,
                              void* d_out, int out_size, void* d_ws, size_t ws_size,
                              hipStream_t stream) {
    const float* ge        = (const float*)d_in[0];
    const float* utter     = (const float*)d_in[1];
    const int*   mi        = (const int*)d_in[2];
    const int*   mbi       = (const int*)d_in[3];
    const int*   sel       = (const int*)d_in[4];
    const int*   selb      = (const int*)d_in[5];
    const int*   selg      = (const int*)d_in[6];
    const int*   grpb      = (const int*)d_in[7];
    const int*   lastI     = (const int*)d_in[8];
    const int*   intentI   = (const int*)d_in[9];
    const float* masks     = (const float*)d_in[10];
    const float* attW      = (const float*)d_in[11];
    const float* attV      = (const float*)d_in[12];
    const float* W1w       = (const float*)d_in[13];
    const float* W1b       = (const float*)d_in[14];
    const float* W2w       = (const float*)d_in[15];
    const float* W2b       = (const float*)d_in[16];
    const float* intentEmb = (const float*)d_in[17];
    float* ws  = (float*)d_ws;
    float* out = (float*)d_out;

    bool full = ws_size >= WS_TOTAL_BYTES;

    if (full) {
        kP<true><<<dim3(NPB + MCB + KCB), dim3(256), 0, stream>>>(
            ge, attW, attV, mi, mbi, sel, selb, selg, ws);
        kA2n<<<dim3(2000), dim3(256), 0, stream>>>(ws);
        kBW<<<dim3(128), dim3(64), 0, stream>>>(ge, utter, grpb, lastI, intentI,
                                                W1w, W1b, W2w, W2b, intentEmb, ws);
        kCn<<<dim3(1024), dim3(512), 0, stream>>>(utter, masks, ws, out);
    } else {
        kP<false><<<dim3(NPB), dim3(256), 0, stream>>>(
            ge, attW, attV, mi, mbi, sel, selb, selg, ws);
        kA2_fb<<<dim3(2000), dim3(256), 0, stream>>>(ge, mi, mbi, ws);
        kBW<<<dim3(128), dim3(64), 0, stream>>>(ge, utter, grpb, lastI, intentI,
                                                W1w, W1b, W2w, W2b, intentEmb, ws);
        kC_fb<<<dim3(1024), dim3(512), 0, stream>>>(ge, utter, sel, selb, selg,
                                                    masks, ws, out);
    }
}